// Round 5
// baseline (364.383 us; speedup 1.0000x reference)
//
#include <hip/hip_runtime.h>
#include <stdint.h>

#define M_DIM 8192
#define N_DIM 8192
#define K_DIM 1024
#define BK    128

typedef int int4v __attribute__((ext_vector_type(4)));

// ---- async global->LDS, 16B per lane ----
__device__ __forceinline__ void gload16(const char* g, char* l) {
    __builtin_amdgcn_global_load_lds(
        (__attribute__((address_space(1))) void*)(void*)const_cast<char*>(g),
        (__attribute__((address_space(3))) void*)l,
        16, 0, 0);
}

__device__ __forceinline__ int sat8(int v) {
    v = v > 127 ? 127 : v;
    v = v < -128 ? -128 : v;
    return v;
}

// ---- fused pack: blocks [0,8192) pack A; blocks [8192,10240) transpose-pack B ----
__global__ __launch_bounds__(256) void pack_ab_kernel(const int* __restrict__ a,
                                                      const int* __restrict__ b,
                                                      int* __restrict__ outA,
                                                      char* __restrict__ outB) {
    __shared__ char tile[64][68];               // used by B-blocks only
    const int t = threadIdx.x;
    if (blockIdx.x < 8192) {
        // pack a: int32 [M][K] -> int8 [M][K], 4 elems/thread, coalesced
        int i = blockIdx.x * 256 + t;
        int4 v = ((const int4*)a)[i];
        outA[i] = (v.x & 0xff) | ((v.y & 0xff) << 8) |
                  ((v.z & 0xff) << 16) | ((v.w & 0xff) << 24);
        return;
    }
    // pack b: int32 [K][N] -> int8 [N][K] (transpose via LDS tile)
    const int bx = blockIdx.x - 8192;           // 0..2047
    const int n0 = (bx & 127) * 64;
    const int k0 = (bx >> 7) * 64;
    const int tr  = t >> 4;                     // 0..15
    const int tc4 = (t & 15) << 2;              // 0,4,..,60
#pragma unroll
    for (int j = 0; j < 4; ++j) {
        int row = tr + j * 16;                  // k within tile
        int4 v = *(const int4*)&b[(size_t)(k0 + row) * N_DIM + n0 + tc4];
        tile[row][tc4 + 0] = (char)v.x;
        tile[row][tc4 + 1] = (char)v.y;
        tile[row][tc4 + 2] = (char)v.z;
        tile[row][tc4 + 3] = (char)v.w;
    }
    __syncthreads();
#pragma unroll
    for (int j = 0; j < 4; ++j) {
        int n = tr + j * 16;                    // n within tile
        int pk = (tile[tc4 + 0][n] & 0xff) |
                 ((tile[tc4 + 1][n] & 0xff) << 8) |
                 ((tile[tc4 + 2][n] & 0xff) << 16) |
                 ((tile[tc4 + 3][n] & 0xff) << 24);
        *(int*)&outB[(size_t)(n0 + n) * K_DIM + k0 + tc4] = pk;
    }
}

// ---- GEMM: 128x128 tile, BK=128, 4 waves (verified R2 core) + LDS-transposed
//      dwordx4 epilogue ----
// R4 post-mortem: conflicts (R2), schedule (R3), occupancy+MFMA shape (R4) all
// null at 363-373us. The invariant across all variants is the VMEM instruction
// stream: 67M global_load_lds (16B) + 67M global_store_dword (scalar, forced by
// the MFMA C-layout's row interleave) = 524K VMEM instr/CU ~ the gemm's ~170us
// at ~1 VMEM issue/cyc/CU. This round eliminates 3/4 of the store instructions:
// transpose acc through the (post-loop idle) LDS so each lane stores 4
// consecutive ints (global_store_dwordx4). Per-wave private 32x68-int padded
// region: stride 68 makes scalar writes 2-way (free, m136) and b128 reads
// bank-uniform; regions are disjoint -> no cross-wave sync. K-loop unchanged.
__global__ __launch_bounds__(256) void gemm_i8_kernel(const char* __restrict__ A8,
                                                      const char* __restrict__ B8,
                                                      int* __restrict__ C) {
    // K-loop view: As = smem[0:16K), Bs = smem[16K:32K)  (2 x [k64-half][row][64B])
    // epilogue view: 4 waves x 32x68-int regions = 34816 B
    __shared__ __align__(16) char smem[4 * 8704];
    char* As = smem;
    char* Bs = smem + 16384;

    const int t    = threadIdx.x;
    const int bn   = blockIdx.x;
    const int bm   = blockIdx.y;
    const int lane = t & 63;
    const int wave = t >> 6;
    const int wm   = wave >> 1;                  // 2x2 wave grid, 64x64 per wave
    const int wn   = wave & 1;
    const int quad = lane >> 4;
    const int l16  = lane & 15;

    const size_t aBase = (size_t)(bm * 128) * K_DIM;
    const size_t bBase = (size_t)(bn * 128) * K_DIM;

    // staging: 4 slots/operand/thread, 16 B each
    const int sr = t >> 2;                       // row within 64-row half
    // T2 swizzle (rule 21): source chunk (t&3)^((t>>3)&3), LDS dest linear
    const int swzc = (((t & 3) ^ ((t >> 3) & 3)) << 4);
    // swizzled read chunk byte offset (per-lane constant)
    const int laneByte = ((quad ^ ((l16 >> 1) & 3)) << 4);

    int4v acc[4][4] = {};

    for (int kt = 0; kt < K_DIM / BK; ++kt) {
        const int kOff = kt * BK;
#pragma unroll
        for (int s = 0; s < 4; ++s) {
            const int p = s >> 1;                // K64-half
            const int rr = ((s & 1) << 6) + sr;  // tile row
            const int f = s * 4096 + t * 16;     // LDS flat offset (linear dest)
            gload16(A8 + aBase + (size_t)rr * K_DIM + kOff + p * 64 + swzc, As + f);
            gload16(B8 + bBase + (size_t)rr * K_DIM + kOff + p * 64 + swzc, Bs + f);
        }
        __syncthreads();   // drains vmcnt -> staged data visible

#pragma unroll
        for (int h = 0; h < 2; ++h) {            // two K64-halves per stage
            int4v af[4], bf[4];
#pragma unroll
            for (int mi = 0; mi < 4; ++mi)
                af[mi] = *(const int4v*)
                    &As[h * 8192 + (wm * 64 + mi * 16 + l16) * 64 + laneByte];
#pragma unroll
            for (int ni = 0; ni < 4; ++ni)
                bf[ni] = *(const int4v*)
                    &Bs[h * 8192 + (wn * 64 + ni * 16 + l16) * 64 + laneByte];

#pragma unroll
            for (int mi = 0; mi < 4; ++mi)
#pragma unroll
                for (int ni = 0; ni < 4; ++ni)
                    acc[mi][ni] = __builtin_amdgcn_mfma_i32_16x16x64_i8(
                        af[mi], bf[ni], acc[mi][ni], 0, 0, 0);
        }

        __syncthreads();   // LDS reads done before next stage overwrites
    }
    // after final barrier no wave touches As/Bs for the K-loop again; LDS is
    // repurposed per-wave (disjoint regions, no further barrier needed).

    // epilogue: acc (C/D layout: col=l16, row=4*quad+reg) -> per-wave LDS
    // transpose region (32 rows x 68-int padded stride) -> dwordx4 stores.
    int* lw = (int*)(smem + wave * 8704);        // 32*68 ints = 8704 B
    const int mW = bm * 128 + wm * 64;
    const int nW = bn * 128 + wn * 64;
#pragma unroll
    for (int rnd = 0; rnd < 2; ++rnd) {
#pragma unroll
        for (int mh = 0; mh < 2; ++mh) {         // mi = rnd*2 + mh
            const int mi = rnd * 2 + mh;
#pragma unroll
            for (int ni = 0; ni < 4; ++ni)
#pragma unroll
                for (int r = 0; r < 4; ++r)
                    lw[(mh * 16 + quad * 4 + r) * 68 + ni * 16 + l16] =
                        sat8(acc[mi][ni][r]);
        }
        // same-wave DS ordering: compiler inserts lgkmcnt before dependent reads
#pragma unroll
        for (int rr = 0; rr < 8; ++rr) {
            const int R = rr * 4 + quad;         // local row 0..31
            const int4v v = *(const int4v*)&lw[R * 68 + l16 * 4];
            *(int4v*)&C[(size_t)(mW + rnd * 32 + R) * N_DIM + nW + l16 * 4] = v;
        }
        // round 2 writes ordered after round 1 reads by in-order per-wave DS pipe
    }
}

// ---- fallback (only if ws_size < 16MB): direct int32 GEMM, slow but correct ----
__global__ __launch_bounds__(256) void gemm_naive_kernel(const int* __restrict__ a,
                                                         const int* __restrict__ b,
                                                         int* __restrict__ C) {
    const int col = blockIdx.x * 256 + threadIdx.x;
    const int row = blockIdx.y;
    int acc = 0;
    for (int k = 0; k < K_DIM; ++k)
        acc += a[(size_t)row * K_DIM + k] * b[(size_t)k * N_DIM + col];
    C[(size_t)row * N_DIM + col] = sat8(acc);
}

extern "C" void kernel_launch(void* const* d_in, const int* in_sizes, int n_in,
                              void* d_out, int out_size, void* d_ws, size_t ws_size,
                              hipStream_t stream) {
    const int* a = (const int*)d_in[0];
    const int* b = (const int*)d_in[1];
    // alpha_row (d_in[2]) / alpha_col (d_in[3]) are unused in this variant.
    int* out = (int*)d_out;

    const size_t needed = 2 * (size_t)M_DIM * K_DIM;   // 16 MB packed operands
    if (ws_size < needed) {
        gemm_naive_kernel<<<dim3(N_DIM / 256, M_DIM), 256, 0, stream>>>(a, b, out);
        return;
    }

    char* A8 = (char*)d_ws;                          // 8 MB
    char* B8 = A8 + (size_t)M_DIM * K_DIM;           // 8 MB

    pack_ab_kernel<<<8192 + 2048, 256, 0, stream>>>(a, b, (int*)A8, B8);
    gemm_i8_kernel<<<dim3(N_DIM / 128, M_DIM / 128), 256, 0, stream>>>(A8, B8, out);
}

// Round 6
// 363.095 us; speedup vs baseline: 1.0035x; 1.0035x over previous
//
#include <hip/hip_runtime.h>
#include <stdint.h>

#define M_DIM 8192
#define N_DIM 8192
#define K_DIM 1024
#define BK    128

typedef int int4v __attribute__((ext_vector_type(4)));

// ---- async global->LDS, 16B per lane ----
__device__ __forceinline__ void gload16(const char* g, char* l) {
    __builtin_amdgcn_global_load_lds(
        (__attribute__((address_space(1))) void*)(void*)const_cast<char*>(g),
        (__attribute__((address_space(3))) void*)l,
        16, 0, 0);
}

__device__ __forceinline__ int sat8(int v) {
    v = v > 127 ? 127 : v;
    v = v < -128 ? -128 : v;
    return v;
}

// ---- fused pack: blocks [0,8192) pack A; blocks [8192,10240) transpose-pack B ----
__global__ __launch_bounds__(256) void pack_ab_kernel(const int* __restrict__ a,
                                                      const int* __restrict__ b,
                                                      int* __restrict__ outA,
                                                      char* __restrict__ outB) {
    __shared__ char tile[64][68];               // used by B-blocks only
    const int t = threadIdx.x;
    if (blockIdx.x < 8192) {
        // pack a: int32 [M][K] -> int8 [M][K], 4 elems/thread, coalesced
        int i = blockIdx.x * 256 + t;
        int4 v = ((const int4*)a)[i];
        outA[i] = (v.x & 0xff) | ((v.y & 0xff) << 8) |
                  ((v.z & 0xff) << 16) | ((v.w & 0xff) << 24);
        return;
    }
    // pack b: int32 [K][N] -> int8 [N][K] (transpose via LDS tile)
    const int bx = blockIdx.x - 8192;           // 0..2047
    const int n0 = (bx & 127) * 64;
    const int k0 = (bx >> 7) * 64;
    const int tr  = t >> 4;                     // 0..15
    const int tc4 = (t & 15) << 2;              // 0,4,..,60
#pragma unroll
    for (int j = 0; j < 4; ++j) {
        int row = tr + j * 16;                  // k within tile
        int4 v = *(const int4*)&b[(size_t)(k0 + row) * N_DIM + n0 + tc4];
        tile[row][tc4 + 0] = (char)v.x;
        tile[row][tc4 + 1] = (char)v.y;
        tile[row][tc4 + 2] = (char)v.z;
        tile[row][tc4 + 3] = (char)v.w;
    }
    __syncthreads();
#pragma unroll
    for (int j = 0; j < 4; ++j) {
        int n = tr + j * 16;                    // n within tile
        int pk = (tile[tc4 + 0][n] & 0xff) |
                 ((tile[tc4 + 1][n] & 0xff) << 8) |
                 ((tile[tc4 + 2][n] & 0xff) << 16) |
                 ((tile[tc4 + 3][n] & 0xff) << 24);
        *(int*)&outB[(size_t)(n0 + n) * K_DIM + k0 + tc4] = pk;
    }
}

// ---- GEMM: 128x128 tile, BK=128, 4 waves (verified R5 core) + XCD-banded
//      bm-fast block mapping ----
// R5 post-mortem: conflicts/schedule/occupancy/MFMA-shape/store-count all null
// at 363-364us. The invariant is beyond-L2 operand re-fetch: 128^2 tiles stage
// each byte 64x -> 1 GiB of traffic; in natural bn-fast order each XCD's
// co-resident blocks span all bn, pulling the whole 8 MB B through its private
// 4 MB L2 every bm-row -> staging streams from L3 (~6-7 TB/s ~ 150-170us),
// which no amount of scheduling/occupancy can hide. This round changes ONLY
// the block->tile map: 1-D grid; assuming round-robin bid->XCD dispatch, each
// XCD owns a contiguous 8-row bm-band and walks it bm-FAST (column-major):
//   xcd=bid&7; j=bid>>3; bm=xcd*8+(j&7); bn=j>>3.
// Per-XCD L2 working set = 1 MB A-band + ~12 hot B-strips ~ 2.5 MB < 4 MB;
// each B-strip reused 8x back-to-back. (Prev session's regressing swizzle
// walked bn-fast inside the band -> B still thrashed; this is the fix.)
__global__ __launch_bounds__(256) void gemm_i8_kernel(const char* __restrict__ A8,
                                                      const char* __restrict__ B8,
                                                      int* __restrict__ C) {
    // K-loop view: As = smem[0:16K), Bs = smem[16K:32K)  (2 x [k64-half][row][64B])
    // epilogue view: 4 waves x 32x68-int regions = 34816 B
    __shared__ __align__(16) char smem[4 * 8704];
    char* As = smem;
    char* Bs = smem + 16384;

    const int t    = threadIdx.x;
    // XCD-banded, bm-fast mapping (bijective over 4096 = 8 xcd x 8 band x 64 bn)
    const int xcd  = blockIdx.x & 7;
    const int j    = blockIdx.x >> 3;
    const int bm   = (xcd << 3) | (j & 7);
    const int bn   = j >> 3;
    const int lane = t & 63;
    const int wave = t >> 6;
    const int wm   = wave >> 1;                  // 2x2 wave grid, 64x64 per wave
    const int wn   = wave & 1;
    const int quad = lane >> 4;
    const int l16  = lane & 15;

    const size_t aBase = (size_t)(bm * 128) * K_DIM;
    const size_t bBase = (size_t)(bn * 128) * K_DIM;

    // staging: 4 slots/operand/thread, 16 B each
    const int sr = t >> 2;                       // row within 64-row half
    // T2 swizzle (rule 21): source chunk (t&3)^((t>>3)&3), LDS dest linear
    const int swzc = (((t & 3) ^ ((t >> 3) & 3)) << 4);
    // swizzled read chunk byte offset (per-lane constant)
    const int laneByte = ((quad ^ ((l16 >> 1) & 3)) << 4);

    int4v acc[4][4] = {};

    for (int kt = 0; kt < K_DIM / BK; ++kt) {
        const int kOff = kt * BK;
#pragma unroll
        for (int s = 0; s < 4; ++s) {
            const int p = s >> 1;                // K64-half
            const int rr = ((s & 1) << 6) + sr;  // tile row
            const int f = s * 4096 + t * 16;     // LDS flat offset (linear dest)
            gload16(A8 + aBase + (size_t)rr * K_DIM + kOff + p * 64 + swzc, As + f);
            gload16(B8 + bBase + (size_t)rr * K_DIM + kOff + p * 64 + swzc, Bs + f);
        }
        __syncthreads();   // drains vmcnt -> staged data visible

#pragma unroll
        for (int h = 0; h < 2; ++h) {            // two K64-halves per stage
            int4v af[4], bf[4];
#pragma unroll
            for (int mi = 0; mi < 4; ++mi)
                af[mi] = *(const int4v*)
                    &As[h * 8192 + (wm * 64 + mi * 16 + l16) * 64 + laneByte];
#pragma unroll
            for (int ni = 0; ni < 4; ++ni)
                bf[ni] = *(const int4v*)
                    &Bs[h * 8192 + (wn * 64 + ni * 16 + l16) * 64 + laneByte];

#pragma unroll
            for (int mi = 0; mi < 4; ++mi)
#pragma unroll
                for (int ni = 0; ni < 4; ++ni)
                    acc[mi][ni] = __builtin_amdgcn_mfma_i32_16x16x64_i8(
                        af[mi], bf[ni], acc[mi][ni], 0, 0, 0);
        }

        __syncthreads();   // LDS reads done before next stage overwrites
    }
    // after final barrier no wave touches As/Bs for the K-loop again; LDS is
    // repurposed per-wave (disjoint regions, no further barrier needed).

    // epilogue: acc (C/D layout: col=l16, row=4*quad+reg) -> per-wave LDS
    // transpose region (32 rows x 68-int padded stride) -> dwordx4 stores.
    int* lw = (int*)(smem + wave * 8704);        // 32*68 ints = 8704 B
    const int mW = bm * 128 + wm * 64;
    const int nW = bn * 128 + wn * 64;
#pragma unroll
    for (int rnd = 0; rnd < 2; ++rnd) {
#pragma unroll
        for (int mh = 0; mh < 2; ++mh) {         // mi = rnd*2 + mh
            const int mi = rnd * 2 + mh;
#pragma unroll
            for (int ni = 0; ni < 4; ++ni)
#pragma unroll
                for (int r = 0; r < 4; ++r)
                    lw[(mh * 16 + quad * 4 + r) * 68 + ni * 16 + l16] =
                        sat8(acc[mi][ni][r]);
        }
        // same-wave DS ordering: compiler inserts lgkmcnt before dependent reads
#pragma unroll
        for (int rr = 0; rr < 8; ++rr) {
            const int R = rr * 4 + quad;         // local row 0..31
            const int4v v = *(const int4v*)&lw[R * 68 + l16 * 4];
            *(int4v*)&C[(size_t)(mW + rnd * 32 + R) * N_DIM + nW + l16 * 4] = v;
        }
        // round 2 writes ordered after round 1 reads by in-order per-wave DS pipe
    }
}

// ---- fallback (only if ws_size < 16MB): direct int32 GEMM, slow but correct ----
__global__ __launch_bounds__(256) void gemm_naive_kernel(const int* __restrict__ a,
                                                         const int* __restrict__ b,
                                                         int* __restrict__ C) {
    const int col = blockIdx.x * 256 + threadIdx.x;
    const int row = blockIdx.y;
    int acc = 0;
    for (int k = 0; k < K_DIM; ++k)
        acc += a[(size_t)row * K_DIM + k] * b[(size_t)k * N_DIM + col];
    C[(size_t)row * N_DIM + col] = sat8(acc);
}

extern "C" void kernel_launch(void* const* d_in, const int* in_sizes, int n_in,
                              void* d_out, int out_size, void* d_ws, size_t ws_size,
                              hipStream_t stream) {
    const int* a = (const int*)d_in[0];
    const int* b = (const int*)d_in[1];
    // alpha_row (d_in[2]) / alpha_col (d_in[3]) are unused in this variant.
    int* out = (int*)d_out;

    const size_t needed = 2 * (size_t)M_DIM * K_DIM;   // 16 MB packed operands
    if (ws_size < needed) {
        gemm_naive_kernel<<<dim3(N_DIM / 256, M_DIM), 256, 0, stream>>>(a, b, out);
        return;
    }

    char* A8 = (char*)d_ws;                          // 8 MB
    char* B8 = A8 + (size_t)M_DIM * K_DIM;           // 8 MB

    pack_ab_kernel<<<8192 + 2048, 256, 0, stream>>>(a, b, (int*)A8, B8);
    gemm_i8_kernel<<<4096, 256, 0, stream>>>(A8, B8, out);
}